// Round 2
// baseline (1074.163 us; speedup 1.0000x reference)
//
#include <hip/hip_runtime.h>
#include <hip/hip_bf16.h>

#define N_NODES 100000
#define N_EDGES 3200000
#define D_IN 256
#define HID 256
#define NC 40
#define NB_NODES ((N_NODES + 255) / 256)   /* 391 node-blocks */
#define EB ((N_EDGES + 255) / 256)         /* 12500 edge-blocks */

typedef unsigned short u16;

static __device__ __forceinline__ float bf2f(u16 u) {
  union { unsigned int i; float f; } c; c.i = ((unsigned int)u) << 16; return c.f;
}
static __device__ __forceinline__ u16 f2bf(float f) {
  union { float f; unsigned int i; } c; c.f = f;
  unsigned int x = c.i;
  x += 0x7fffu + ((x >> 16) & 1u);   // round-to-nearest-even
  return (u16)(x >> 16);
}

// ---- degree / dinv ----------------------------------------------------------
__global__ void k_init(float* __restrict__ deg) {
  int i = blockIdx.x * 256 + threadIdx.x;
  if (i < N_NODES) deg[i] = 1.0f;            // self-loop
}
__global__ void k_count(const int* __restrict__ ei, float* __restrict__ deg) {
  int e = blockIdx.x * 256 + threadIdx.x;
  if (e >= N_EDGES) return;
  unsigned d = (unsigned)ei[N_EDGES + e];    // dst half of [2,E] int32
  if (d < N_NODES) atomicAdd(&deg[d], 1.0f);
}
__global__ void k_dinv(const float* __restrict__ deg, float* __restrict__ dinv) {
  int i = blockIdx.x * 256 + threadIdx.x;
  if (i < N_NODES) dinv[i] = rsqrtf(deg[i]); // deg >= 1 always
}

// ---- CSR build: 3-phase exclusive scan of in-degree, then scatter -----------
__global__ __launch_bounds__(256) void k_scan1(const float* __restrict__ deg,
    int* __restrict__ rp, int* __restrict__ bsums) {
  __shared__ int s[256];
  int t = threadIdx.x, i = blockIdx.x * 256 + t;
  int v = (i < N_NODES) ? ((int)deg[i] - 1) : 0;
  s[t] = v;
  __syncthreads();
  for (int off = 1; off < 256; off <<= 1) {
    int add = (t >= off) ? s[t - off] : 0;
    __syncthreads();
    s[t] += add;
    __syncthreads();
  }
  if (i < N_NODES) rp[i] = s[t] - v;         // local exclusive
  if (t == 255) bsums[blockIdx.x] = s[255];
}
__global__ __launch_bounds__(512) void k_scan2(const int* __restrict__ bsums,
                                               int* __restrict__ boffs) {
  __shared__ int s[512];
  int t = threadIdx.x;
  int v = (t < NB_NODES) ? bsums[t] : 0;
  s[t] = v;
  __syncthreads();
  for (int off = 1; off < 512; off <<= 1) {
    int add = (t >= off) ? s[t - off] : 0;
    __syncthreads();
    s[t] += add;
    __syncthreads();
  }
  boffs[t] = s[t] - v;
}
__global__ void k_scan3(int* __restrict__ rp, const int* __restrict__ boffs,
                        int* __restrict__ cursor) {
  int i = blockIdx.x * 256 + threadIdx.x;
  if (i < N_NODES) {
    int v = rp[i] + boffs[blockIdx.x];
    rp[i] = v;
    cursor[i] = v;
  }
  if (i == 0) rp[N_NODES] = N_EDGES;
}
__global__ void k_scatter(const int* __restrict__ ei,
    const float* __restrict__ dinv, int* __restrict__ cursor,
    int2* __restrict__ ed) {
  int e = blockIdx.x * 256 + threadIdx.x;
  if (e >= N_EDGES) return;
  unsigned s = (unsigned)ei[e];
  unsigned d = (unsigned)ei[N_EDGES + e];
  if (s >= N_NODES || d >= N_NODES) return;  // never taken; fault guard
  int pos = atomicAdd(&cursor[d], 1);
  if ((unsigned)pos < N_EDGES)
    ed[pos] = make_int2((int)s, __float_as_int(dinv[s] * dinv[d]));
}

// ---- GEMM1: y[100000,256] = x @ W1 (f32 in, bf16 out). 64x64x16 tiles -------
__global__ __launch_bounds__(256) void k_gemm1(const float* __restrict__ x,
    const float* __restrict__ W1, u16* __restrict__ y) {
  __shared__ float As[16][68];   // transposed A tile: As[k][m]
  __shared__ float Bs[16][68];
  int tid = threadIdx.x;
  int tx = tid & 15, ty = tid >> 4;
  int row0 = blockIdx.x * 64;
  int col0 = blockIdx.y * 64;
  int lm = tid >> 2;             // A-load row 0..63
  int lk = (tid & 3) * 4;        // A-load k-quad
  int bk = tid >> 4;             // B-load k 0..15
  int bn = (tid & 15) * 4;       // B-load col-quad
  float acc[4][4] = {};
  for (int k0 = 0; k0 < D_IN; k0 += 16) {
    float4 a4 = make_float4(0.f, 0.f, 0.f, 0.f);
    int ar = row0 + lm;
    if (ar < N_NODES) a4 = *(const float4*)(x + (size_t)ar * D_IN + k0 + lk);
    float4 b4 = *(const float4*)(W1 + (size_t)(k0 + bk) * HID + col0 + bn);
    __syncthreads();
    As[lk + 0][lm] = a4.x;
    As[lk + 1][lm] = a4.y;
    As[lk + 2][lm] = a4.z;
    As[lk + 3][lm] = a4.w;
    *(float4*)&Bs[bk][bn] = b4;
    __syncthreads();
#pragma unroll
    for (int kk = 0; kk < 16; ++kk) {
      float4 a = *(const float4*)&As[kk][ty * 4];
      float4 b = *(const float4*)&Bs[kk][tx * 4];
      acc[0][0] += a.x * b.x; acc[0][1] += a.x * b.y; acc[0][2] += a.x * b.z; acc[0][3] += a.x * b.w;
      acc[1][0] += a.y * b.x; acc[1][1] += a.y * b.y; acc[1][2] += a.y * b.z; acc[1][3] += a.y * b.w;
      acc[2][0] += a.z * b.x; acc[2][1] += a.z * b.y; acc[2][2] += a.z * b.z; acc[2][3] += a.z * b.w;
      acc[3][0] += a.w * b.x; acc[3][1] += a.w * b.y; acc[3][2] += a.w * b.z; acc[3][3] += a.w * b.w;
    }
  }
#pragma unroll
  for (int i = 0; i < 4; ++i) {
    int r = row0 + ty * 4 + i;
    if (r < N_NODES) {
      ushort4 o;
      o.x = f2bf(acc[i][0]); o.y = f2bf(acc[i][1]);
      o.z = f2bf(acc[i][2]); o.w = f2bf(acc[i][3]);
      *(ushort4*)(y + (size_t)r * HID + col0 + tx * 4) = o;
    }
  }
}

// ---- SpMM1: h1 = relu(A @ y + b1), pull-style, one wave per dst row ---------
__global__ __launch_bounds__(256) void k_spmm1(const u16* __restrict__ y,
    const int2* __restrict__ ed, const int* __restrict__ rp,
    const float* __restrict__ dinv, const float* __restrict__ b1,
    u16* __restrict__ h1) {
  int lane = threadIdx.x & 63;
  int row = (blockIdx.x << 2) + (threadIdx.x >> 6);
  float di = dinv[row];
  float wsl = di * di;
  ushort4 v = *(const ushort4*)(y + (size_t)row * HID + lane * 4);
  float a0 = wsl * bf2f(v.x), a1 = wsl * bf2f(v.y);
  float a2 = wsl * bf2f(v.z), a3 = wsl * bf2f(v.w);
  int e = rp[row], e1 = rp[row + 1];
  for (; e + 2 <= e1; e += 2) {
    int2 m0 = ed[e];
    int2 m1 = ed[e + 1];
    ushort4 u0 = *(const ushort4*)(y + (size_t)m0.x * HID + lane * 4);
    ushort4 u1 = *(const ushort4*)(y + (size_t)m1.x * HID + lane * 4);
    float w0 = __int_as_float(m0.y), w1 = __int_as_float(m1.y);
    a0 += w0 * bf2f(u0.x) + w1 * bf2f(u1.x);
    a1 += w0 * bf2f(u0.y) + w1 * bf2f(u1.y);
    a2 += w0 * bf2f(u0.z) + w1 * bf2f(u1.z);
    a3 += w0 * bf2f(u0.w) + w1 * bf2f(u1.w);
  }
  if (e < e1) {
    int2 m = ed[e];
    ushort4 u = *(const ushort4*)(y + (size_t)m.x * HID + lane * 4);
    float w = __int_as_float(m.y);
    a0 += w * bf2f(u.x); a1 += w * bf2f(u.y);
    a2 += w * bf2f(u.z); a3 += w * bf2f(u.w);
  }
  float4 bb = *(const float4*)(b1 + lane * 4);
  a0 = fmaxf(a0 + bb.x, 0.f);
  a1 = fmaxf(a1 + bb.y, 0.f);
  a2 = fmaxf(a2 + bb.z, 0.f);
  a3 = fmaxf(a3 + bb.w, 0.f);
  ushort4 o;
  o.x = f2bf(a0); o.y = f2bf(a1); o.z = f2bf(a2); o.w = f2bf(a3);
  *(ushort4*)(h1 + (size_t)row * HID + lane * 4) = o;
}

// ---- GEMM2: z[100000,40] = h1 @ W2 (bf16 in, f32 out), W2 staged in LDS -----
__global__ __launch_bounds__(256) void k_gemm2(const u16* __restrict__ h1,
    const float* __restrict__ W2, float* __restrict__ z) {
  __shared__ float W2s[HID * NC];   // 40 KB
  for (int j = threadIdx.x; j < HID * NC; j += 256) W2s[j] = W2[j];
  __syncthreads();
  int idx = blockIdx.x * 256 + threadIdx.x;
  int r = idx / 10, q = idx % 10;   // 10 col-quads of 4 => 40 cols
  if (r >= N_NODES) return;
  const u16* hr = h1 + (size_t)r * HID;
  float ax = 0.f, ay = 0.f, az = 0.f, aw = 0.f;
  for (int k = 0; k < HID; k += 4) {
    ushort4 hv = *(const ushort4*)(hr + k);
    float h0 = bf2f(hv.x), h1v = bf2f(hv.y), h2 = bf2f(hv.z), h3 = bf2f(hv.w);
    float4 w0 = *(const float4*)&W2s[(k + 0) * NC + q * 4];
    float4 w1 = *(const float4*)&W2s[(k + 1) * NC + q * 4];
    float4 w2 = *(const float4*)&W2s[(k + 2) * NC + q * 4];
    float4 w3 = *(const float4*)&W2s[(k + 3) * NC + q * 4];
    ax += h0 * w0.x + h1v * w1.x + h2 * w2.x + h3 * w3.x;
    ay += h0 * w0.y + h1v * w1.y + h2 * w2.y + h3 * w3.y;
    az += h0 * w0.z + h1v * w1.z + h2 * w2.z + h3 * w3.z;
    aw += h0 * w0.w + h1v * w1.w + h2 * w2.w + h3 * w3.w;
  }
  float4 o = make_float4(ax, ay, az, aw);
  *(float4*)(z + (size_t)r * NC + q * 4) = o;
}

// ---- SpMM2 + bias + log_softmax fused: one wave per row ---------------------
__global__ __launch_bounds__(256) void k_spmm2(const float* __restrict__ z,
    const int2* __restrict__ ed, const int* __restrict__ rp,
    const float* __restrict__ dinv, const float* __restrict__ b2,
    float* __restrict__ out) {
  int lane = threadIdx.x & 63;
  int row = (blockIdx.x << 2) + (threadIdx.x >> 6);
  int col = (lane < NC) ? lane : 0;
  float di = dinv[row];
  float acc = di * di * z[(size_t)row * NC + col];
  int e = rp[row], e1 = rp[row + 1];
  for (; e + 2 <= e1; e += 2) {
    int2 m0 = ed[e];
    int2 m1 = ed[e + 1];
    float z0 = z[(size_t)m0.x * NC + col];
    float z1 = z[(size_t)m1.x * NC + col];
    acc += __int_as_float(m0.y) * z0 + __int_as_float(m1.y) * z1;
  }
  if (e < e1) {
    int2 m = ed[e];
    acc += __int_as_float(m.y) * z[(size_t)m.x * NC + col];
  }
  acc += b2[col];
  float mv = (lane < NC) ? acc : -3.0e38f;
  for (int off = 32; off > 0; off >>= 1) mv = fmaxf(mv, __shfl_xor(mv, off));
  float ex = (lane < NC) ? expf(acc - mv) : 0.f;
  float sum = ex;
  for (int off = 32; off > 0; off >>= 1) sum += __shfl_xor(sum, off);
  float res = acc - mv - logf(sum);
  if (lane < NC) out[(size_t)row * NC + lane] = res;
}

extern "C" void kernel_launch(void* const* d_in, const int* in_sizes, int n_in,
                              void* d_out, int out_size, void* d_ws, size_t ws_size,
                              hipStream_t stream) {
  const float* x  = (const float*)d_in[0];
  const int*   ei = (const int*)d_in[1];     // int inputs delivered as int32
  const float* W1 = (const float*)d_in[2];
  const float* b1 = (const float*)d_in[3];
  const float* W2 = (const float*)d_in[4];
  const float* b2 = (const float*)d_in[5];
  float* out = (float*)d_out;

  char* ws = (char*)d_ws;
  size_t off = 0;
  auto alloc = [&](size_t bytes) {
    char* p = ws + off;
    off = (off + bytes + 255) & ~(size_t)255;
    return p;
  };
  float* deg    = (float*)alloc((size_t)N_NODES * 4);
  float* dinv   = (float*)alloc((size_t)N_NODES * 4);
  int*   rp     = (int*)  alloc((size_t)(N_NODES + 1) * 4);
  int*   cursor = (int*)  alloc((size_t)N_NODES * 4);
  int*   bsums  = (int*)  alloc((size_t)NB_NODES * 4);
  int*   boffs  = (int*)  alloc((size_t)512 * 4);
  int2*  ed     = (int2*) alloc((size_t)N_EDGES * 8);       // 25.6 MB
  u16*   y      = (u16*)  alloc((size_t)N_NODES * HID * 2); // 51.2 MB
  u16*   h1     = (u16*)  alloc((size_t)N_NODES * HID * 2); // 51.2 MB
  float* z      = (float*)y;  // reuse: y is dead after k_spmm1 (saves 16 MB)

  // degree + dinv
  k_init<<<NB_NODES, 256, 0, stream>>>(deg);
  k_count<<<EB, 256, 0, stream>>>(ei, deg);
  k_dinv<<<NB_NODES, 256, 0, stream>>>(deg, dinv);
  // CSR by dst
  k_scan1<<<NB_NODES, 256, 0, stream>>>(deg, rp, bsums);
  k_scan2<<<1, 512, 0, stream>>>(bsums, boffs);
  k_scan3<<<NB_NODES, 256, 0, stream>>>(rp, boffs, cursor);
  k_scatter<<<EB, 256, 0, stream>>>(ei, dinv, cursor, ed);
  // y = x @ W1 (bf16)
  k_gemm1<<<dim3((N_NODES + 63) / 64, HID / 64), 256, 0, stream>>>(x, W1, y);
  // h1 = relu(A y + b1) (bf16)
  k_spmm1<<<N_NODES / 4, 256, 0, stream>>>(y, ed, rp, dinv, b1, h1);
  // z = h1 @ W2 (f32)  [z aliases y]
  k_gemm2<<<(N_NODES * 10 + 255) / 256, 256, 0, stream>>>(h1, W2, z);
  // out = log_softmax(A z + b2)
  k_spmm2<<<N_NODES / 4, 256, 0, stream>>>(z, ed, rp, dinv, b2, out);
}

// Round 3
// 916.510 us; speedup vs baseline: 1.1720x; 1.1720x over previous
//
#include <hip/hip_runtime.h>
#include <hip/hip_bf16.h>

#define N_NODES 100000
#define N_EDGES 3200000
#define D_IN 256
#define HID 256
#define NC 40
#define NPAD 100096                        /* 782 * 128, padded row count */
#define NB_NODES ((N_NODES + 255) / 256)   /* 391 node-blocks */
#define EB ((N_EDGES + 255) / 256)         /* 12500 edge-blocks */

typedef unsigned short u16;
typedef unsigned int u32;
typedef __attribute__((ext_vector_type(8))) short bf16x8;
typedef __attribute__((ext_vector_type(4))) float f32x4;
typedef __attribute__((ext_vector_type(2))) float f32x2;

static __device__ __forceinline__ float bf2f(u16 u) {
  union { unsigned int i; float f; } c; c.i = ((unsigned int)u) << 16; return c.f;
}
static __device__ __forceinline__ u16 f2bf(float f) {
  union { float f; unsigned int i; } c; c.f = f;
  unsigned int x = c.i;
  x += 0x7fffu + ((x >> 16) & 1u);   // round-to-nearest-even
  return (u16)(x >> 16);
}

// ---- degree / dinv ----------------------------------------------------------
__global__ void k_init(float* __restrict__ deg) {
  int i = blockIdx.x * 256 + threadIdx.x;
  if (i < N_NODES) deg[i] = 1.0f;            // self-loop
}
__global__ void k_count(const int* __restrict__ ei, float* __restrict__ deg) {
  int e = blockIdx.x * 256 + threadIdx.x;
  if (e >= N_EDGES) return;
  unsigned d = (unsigned)ei[N_EDGES + e];
  if (d < N_NODES) atomicAdd(&deg[d], 1.0f);
}
__global__ void k_dinv(const float* __restrict__ deg, float* __restrict__ dinv) {
  int i = blockIdx.x * 256 + threadIdx.x;
  if (i < N_NODES) dinv[i] = rsqrtf(deg[i]);
}

// ---- CSR build --------------------------------------------------------------
__global__ __launch_bounds__(256) void k_scan1(const float* __restrict__ deg,
    int* __restrict__ rp, int* __restrict__ bsums) {
  __shared__ int s[256];
  int t = threadIdx.x, i = blockIdx.x * 256 + t;
  int v = (i < N_NODES) ? ((int)deg[i] - 1) : 0;
  s[t] = v;
  __syncthreads();
  for (int off = 1; off < 256; off <<= 1) {
    int add = (t >= off) ? s[t - off] : 0;
    __syncthreads();
    s[t] += add;
    __syncthreads();
  }
  if (i < N_NODES) rp[i] = s[t] - v;
  if (t == 255) bsums[blockIdx.x] = s[255];
}
__global__ __launch_bounds__(512) void k_scan2(const int* __restrict__ bsums,
                                               int* __restrict__ boffs) {
  __shared__ int s[512];
  int t = threadIdx.x;
  int v = (t < NB_NODES) ? bsums[t] : 0;
  s[t] = v;
  __syncthreads();
  for (int off = 1; off < 512; off <<= 1) {
    int add = (t >= off) ? s[t - off] : 0;
    __syncthreads();
    s[t] += add;
    __syncthreads();
  }
  boffs[t] = s[t] - v;
}
__global__ void k_scan3(int* __restrict__ rp, const int* __restrict__ boffs,
                        int* __restrict__ cursor) {
  int i = blockIdx.x * 256 + threadIdx.x;
  if (i < N_NODES) {
    int v = rp[i] + boffs[blockIdx.x];
    rp[i] = v;
    cursor[i] = v;
  }
  if (i == 0) rp[N_NODES] = N_EDGES;
}
__global__ void k_scatter(const int* __restrict__ ei,
    const float* __restrict__ dinv, int* __restrict__ cursor,
    int2* __restrict__ ed) {
  int e = blockIdx.x * 256 + threadIdx.x;
  if (e >= N_EDGES) return;
  unsigned s = (unsigned)ei[e];
  unsigned d = (unsigned)ei[N_EDGES + e];
  if (s >= N_NODES || d >= N_NODES) return;
  int pos = atomicAdd(&cursor[d], 1);
  if ((unsigned)pos < N_EDGES)
    ed[pos] = make_int2((int)s, __float_as_int(dinv[s] * dinv[d]));
}

// ---- converts: x -> bf16, W1 -> W1^T bf16 -----------------------------------
__global__ void k_xb(const float* __restrict__ x, u16* __restrict__ xb) {
  int i = blockIdx.x * 256 + threadIdx.x;      // one float4 each
  if (i >= (N_NODES * D_IN) / 4) return;
  float4 v = ((const float4*)x)[i];
  ushort4 o; o.x = f2bf(v.x); o.y = f2bf(v.y); o.z = f2bf(v.z); o.w = f2bf(v.w);
  ((ushort4*)xb)[i] = o;
}
__global__ void k_w1t(const float* __restrict__ W1, u16* __restrict__ w1t) {
  int n = blockIdx.x, k = threadIdx.x;         // 256 x 256
  w1t[n * 256 + k] = f2bf(W1[k * 256 + n]);
}

// ---- GEMM1 (MFMA bf16): y[100000,256]fp8 = xb @ W1, 128x128 tile ------------
__global__ __launch_bounds__(256) void k_gemm1(const u16* __restrict__ xb,
    const u16* __restrict__ w1t, unsigned char* __restrict__ y) {
  __shared__ char smem[20480];
  short* sA = (short*)smem;                    // [128][40] bf16 (pad 8)
  short* sB = (short*)(smem + 10240);          // [128][40]
  int tid = threadIdx.x;
  int wave = tid >> 6, lane = tid & 63;
  int lq = lane >> 4, lr = lane & 15;
  int wm = (wave >> 1) * 64, wn = (wave & 1) * 64;
  int row0 = blockIdx.x * 128;
  int col0 = blockIdx.y * 128;
  int sr = tid >> 1;                           // staging row 0..127
  int sh = (tid & 1) * 16;                     // k-half in shorts
  const u16* ax = xb + (size_t)(row0 + sr) * 256 + sh;   // rows padded to NPAD
  const u16* bx = w1t + (size_t)(col0 + sr) * 256 + sh;
  f32x4 acc[4][4] = {};
  for (int k0 = 0; k0 < 256; k0 += 32) {
    uint4 va0 = *(const uint4*)(ax + k0);
    uint4 va1 = *(const uint4*)(ax + k0 + 8);
    uint4 vb0 = *(const uint4*)(bx + k0);
    uint4 vb1 = *(const uint4*)(bx + k0 + 8);
    __syncthreads();
    *(uint4*)&sA[sr * 40 + sh] = va0;
    *(uint4*)&sA[sr * 40 + sh + 8] = va1;
    *(uint4*)&sB[sr * 40 + sh] = vb0;
    *(uint4*)&sB[sr * 40 + sh + 8] = vb1;
    __syncthreads();
    bf16x8 af[4], bfr[4];
#pragma unroll
    for (int mt = 0; mt < 4; ++mt)
      af[mt] = *(const bf16x8*)&sA[(wm + mt * 16 + lr) * 40 + lq * 8];
#pragma unroll
    for (int nt = 0; nt < 4; ++nt)
      bfr[nt] = *(const bf16x8*)&sB[(wn + nt * 16 + lr) * 40 + lq * 8];
#pragma unroll
    for (int mt = 0; mt < 4; ++mt)
#pragma unroll
      for (int nt = 0; nt < 4; ++nt)
        acc[mt][nt] = __builtin_amdgcn_mfma_f32_16x16x32_bf16(
            af[mt], bfr[nt], acc[mt][nt], 0, 0, 0);
  }
  // epilogue: fp8 via LDS transpose (C/D: col=lane&15, row=(lane>>4)*4+reg)
  __syncthreads();
#pragma unroll
  for (int mt = 0; mt < 4; ++mt)
#pragma unroll
    for (int nt = 0; nt < 4; ++nt) {
      int c = wn + nt * 16 + lr;
#pragma unroll
      for (int i = 0; i < 4; ++i) {
        int r = wm + mt * 16 + lq * 4 + i;
        int pk = __builtin_amdgcn_cvt_pk_fp8_f32(acc[mt][nt][i], acc[mt][nt][i], 0, false);
        smem[r * 144 + c] = (char)(pk & 0xFF);
      }
    }
  __syncthreads();
  int orow = row0 + sr;
  if (orow < N_NODES) {
    unsigned char* dst = y + (size_t)orow * 256 + col0 + (tid & 1) * 64;
    const char* srcp = smem + sr * 144 + (tid & 1) * 64;
#pragma unroll
    for (int j = 0; j < 4; ++j)
      ((uint4*)dst)[j] = *(const uint4*)(srcp + j * 16);
  }
}

// ---- SpMM1: h1 = relu(A @ y + b1), y is fp8, one wave per dst row -----------
__global__ __launch_bounds__(256) void k_spmm1(const u32* __restrict__ y32,
    const int2* __restrict__ ed, const int* __restrict__ rp,
    const float* __restrict__ dinv, const float* __restrict__ b1,
    u16* __restrict__ h1) {
  int lane = threadIdx.x & 63;
  int row = (blockIdx.x << 2) + (threadIdx.x >> 6);
  float di = dinv[row];
  float wsl = di * di;
  u32 v = y32[(size_t)row * 64 + lane];
  f32x2 lo = __builtin_amdgcn_cvt_pk_f32_fp8(v, false);
  f32x2 hi = __builtin_amdgcn_cvt_pk_f32_fp8(v, true);
  float a0 = wsl * lo.x, a1 = wsl * lo.y, a2 = wsl * hi.x, a3 = wsl * hi.y;
  int e = rp[row], e1 = rp[row + 1];
  for (; e + 2 <= e1; e += 2) {
    int2 m0 = ed[e];
    int2 m1 = ed[e + 1];
    u32 u0 = y32[(size_t)m0.x * 64 + lane];
    u32 u1 = y32[(size_t)m1.x * 64 + lane];
    float w0 = __int_as_float(m0.y), w1 = __int_as_float(m1.y);
    f32x2 l0 = __builtin_amdgcn_cvt_pk_f32_fp8(u0, false);
    f32x2 h0 = __builtin_amdgcn_cvt_pk_f32_fp8(u0, true);
    f32x2 l1 = __builtin_amdgcn_cvt_pk_f32_fp8(u1, false);
    f32x2 h1v = __builtin_amdgcn_cvt_pk_f32_fp8(u1, true);
    a0 += w0 * l0.x + w1 * l1.x;
    a1 += w0 * l0.y + w1 * l1.y;
    a2 += w0 * h0.x + w1 * h1v.x;
    a3 += w0 * h0.y + w1 * h1v.y;
  }
  if (e < e1) {
    int2 m = ed[e];
    u32 u = y32[(size_t)m.x * 64 + lane];
    float w = __int_as_float(m.y);
    f32x2 l = __builtin_amdgcn_cvt_pk_f32_fp8(u, false);
    f32x2 h = __builtin_amdgcn_cvt_pk_f32_fp8(u, true);
    a0 += w * l.x; a1 += w * l.y; a2 += w * h.x; a3 += w * h.y;
  }
  float4 bb = *(const float4*)(b1 + lane * 4);
  a0 = fmaxf(a0 + bb.x, 0.f);
  a1 = fmaxf(a1 + bb.y, 0.f);
  a2 = fmaxf(a2 + bb.z, 0.f);
  a3 = fmaxf(a3 + bb.w, 0.f);
  ushort4 o;
  o.x = f2bf(a0); o.y = f2bf(a1); o.z = f2bf(a2); o.w = f2bf(a3);
  *(ushort4*)(h1 + (size_t)row * HID + lane * 4) = o;
}

// ---- GEMM2: z[100000,40]bf16 = h1 @ W2, W2 staged in LDS --------------------
__global__ __launch_bounds__(256) void k_gemm2(const u16* __restrict__ h1,
    const float* __restrict__ W2, u16* __restrict__ zb) {
  __shared__ float W2s[HID * NC];   // 40 KB
  for (int j = threadIdx.x; j < HID * NC; j += 256) W2s[j] = W2[j];
  __syncthreads();
  int idx = blockIdx.x * 256 + threadIdx.x;
  int r = idx / 10, q = idx % 10;
  if (r >= N_NODES) return;
  const u16* hr = h1 + (size_t)r * HID;
  float ax = 0.f, ay = 0.f, az = 0.f, aw = 0.f;
  for (int k = 0; k < HID; k += 4) {
    ushort4 hv = *(const ushort4*)(hr + k);
    float h0 = bf2f(hv.x), h1v = bf2f(hv.y), h2 = bf2f(hv.z), h3 = bf2f(hv.w);
    float4 w0 = *(const float4*)&W2s[(k + 0) * NC + q * 4];
    float4 w1 = *(const float4*)&W2s[(k + 1) * NC + q * 4];
    float4 w2 = *(const float4*)&W2s[(k + 2) * NC + q * 4];
    float4 w3 = *(const float4*)&W2s[(k + 3) * NC + q * 4];
    ax += h0 * w0.x + h1v * w1.x + h2 * w2.x + h3 * w3.x;
    ay += h0 * w0.y + h1v * w1.y + h2 * w2.y + h3 * w3.y;
    az += h0 * w0.z + h1v * w1.z + h2 * w2.z + h3 * w3.z;
    aw += h0 * w0.w + h1v * w1.w + h2 * w2.w + h3 * w3.w;
  }
  ushort4 o;
  o.x = f2bf(ax); o.y = f2bf(ay); o.z = f2bf(az); o.w = f2bf(aw);
  *(ushort4*)(zb + (size_t)r * NC + q * 4) = o;
}

// ---- SpMM2 + bias + log_softmax fused (z bf16): one wave per row ------------
__global__ __launch_bounds__(256) void k_spmm2(const u16* __restrict__ zb,
    const int2* __restrict__ ed, const int* __restrict__ rp,
    const float* __restrict__ dinv, const float* __restrict__ b2,
    float* __restrict__ out) {
  int lane = threadIdx.x & 63;
  int row = (blockIdx.x << 2) + (threadIdx.x >> 6);
  int col = (lane < NC) ? lane : 0;
  float di = dinv[row];
  float acc = di * di * bf2f(zb[(size_t)row * NC + col]);
  int e = rp[row], e1 = rp[row + 1];
  for (; e + 2 <= e1; e += 2) {
    int2 m0 = ed[e];
    int2 m1 = ed[e + 1];
    float z0 = bf2f(zb[(size_t)m0.x * NC + col]);
    float z1 = bf2f(zb[(size_t)m1.x * NC + col]);
    acc += __int_as_float(m0.y) * z0 + __int_as_float(m1.y) * z1;
  }
  if (e < e1) {
    int2 m = ed[e];
    acc += __int_as_float(m.y) * bf2f(zb[(size_t)m.x * NC + col]);
  }
  acc += b2[col];
  float mv = (lane < NC) ? acc : -3.0e38f;
  for (int off = 32; off > 0; off >>= 1) mv = fmaxf(mv, __shfl_xor(mv, off));
  float ex = (lane < NC) ? expf(acc - mv) : 0.f;
  float sum = ex;
  for (int off = 32; off > 0; off >>= 1) sum += __shfl_xor(sum, off);
  float res = acc - mv - logf(sum);
  if (lane < NC) out[(size_t)row * NC + lane] = res;
}

extern "C" void kernel_launch(void* const* d_in, const int* in_sizes, int n_in,
                              void* d_out, int out_size, void* d_ws, size_t ws_size,
                              hipStream_t stream) {
  const float* x  = (const float*)d_in[0];
  const int*   ei = (const int*)d_in[1];
  const float* W1 = (const float*)d_in[2];
  const float* b1 = (const float*)d_in[3];
  const float* W2 = (const float*)d_in[4];
  const float* b2 = (const float*)d_in[5];
  float* out = (float*)d_out;

  char* ws = (char*)d_ws;
  size_t off = 0;
  auto alloc = [&](size_t bytes) {
    char* p = ws + off;
    off = (off + bytes + 255) & ~(size_t)255;
    return p;
  };
  float* deg    = (float*)alloc((size_t)N_NODES * 4);
  float* dinv   = (float*)alloc((size_t)N_NODES * 4);
  int*   rp     = (int*)  alloc((size_t)(N_NODES + 1) * 4);
  int*   cursor = (int*)  alloc((size_t)N_NODES * 4);
  int*   bsums  = (int*)  alloc((size_t)NB_NODES * 4);
  int*   boffs  = (int*)  alloc((size_t)512 * 4);
  int2*  ed     = (int2*) alloc((size_t)N_EDGES * 8);          // 25.6 MB
  unsigned char* y = (unsigned char*)alloc((size_t)NPAD * 256); // 25.6 MB fp8
  u16*   xb     = (u16*)  alloc((size_t)NPAD * 256 * 2);        // 51.2 MB bf16
  u16*   w1t    = (u16*)  alloc((size_t)256 * 256 * 2);
  u16*   zb     = (u16*)  alloc((size_t)N_NODES * NC * 2);      // 8 MB bf16
  u16*   h1     = xb;   // xb dead after k_gemm1; reuse for h1

  k_init<<<NB_NODES, 256, 0, stream>>>(deg);
  k_count<<<EB, 256, 0, stream>>>(ei, deg);
  k_dinv<<<NB_NODES, 256, 0, stream>>>(deg, dinv);
  k_scan1<<<NB_NODES, 256, 0, stream>>>(deg, rp, bsums);
  k_scan2<<<1, 512, 0, stream>>>(bsums, boffs);
  k_scan3<<<NB_NODES, 256, 0, stream>>>(rp, boffs, cursor);
  k_scatter<<<EB, 256, 0, stream>>>(ei, dinv, cursor, ed);
  k_xb<<<(N_NODES * D_IN / 4 + 255) / 256, 256, 0, stream>>>(x, xb);
  k_w1t<<<256, 256, 0, stream>>>(W1, w1t);
  k_gemm1<<<dim3(NPAD / 128, 2), 256, 0, stream>>>(xb, w1t, y);
  k_spmm1<<<N_NODES / 4, 256, 0, stream>>>((const u32*)y, ed, rp, dinv, b1, h1);
  k_gemm2<<<(N_NODES * 10 + 255) / 256, 256, 0, stream>>>(h1, W2, zb);
  k_spmm2<<<N_NODES / 4, 256, 0, stream>>>(zb, ed, rp, dinv, b2, out);
}

// Round 4
// 802.258 us; speedup vs baseline: 1.3389x; 1.1424x over previous
//
#include <hip/hip_runtime.h>
#include <hip/hip_bf16.h>

#define N_NODES 100000
#define N_EDGES 3200000
#define D_IN 256
#define HID 256
#define NC 40
#define NB_NODES ((N_NODES + 255) / 256)   /* 391 node-blocks */
#define EB ((N_EDGES + 255) / 256)         /* 12500 edge-blocks */

typedef unsigned short u16;
typedef unsigned int u32;
typedef __attribute__((ext_vector_type(8))) short bf16x8;
typedef __attribute__((ext_vector_type(4))) float f32x4;
typedef __attribute__((ext_vector_type(2))) float f32x2;

static __device__ __forceinline__ float bf2f(u16 u) {
  union { unsigned int i; float f; } c; c.i = ((unsigned int)u) << 16; return c.f;
}
static __device__ __forceinline__ u16 f2bf(float f) {
  union { float f; unsigned int i; } c; c.f = f;
  unsigned int x = c.i;
  x += 0x7fffu + ((x >> 16) & 1u);   // round-to-nearest-even
  return (u16)(x >> 16);
}

// ---- degree / dinv ----------------------------------------------------------
__global__ void k_init(float* __restrict__ deg) {
  int i = blockIdx.x * 256 + threadIdx.x;
  if (i < N_NODES) deg[i] = 1.0f;            // self-loop
}
__global__ void k_count(const int* __restrict__ ei, float* __restrict__ deg) {
  int e = blockIdx.x * 256 + threadIdx.x;
  if (e >= N_EDGES) return;
  unsigned d = (unsigned)ei[N_EDGES + e];
  if (d < N_NODES) atomicAdd(&deg[d], 1.0f);
}
__global__ void k_dinv(const float* __restrict__ deg, float* __restrict__ dinv) {
  int i = blockIdx.x * 256 + threadIdx.x;
  if (i < N_NODES) dinv[i] = rsqrtf(deg[i]);
}

// ---- CSR build --------------------------------------------------------------
__global__ __launch_bounds__(256) void k_scan1(const float* __restrict__ deg,
    int* __restrict__ rp, int* __restrict__ bsums) {
  __shared__ int s[256];
  int t = threadIdx.x, i = blockIdx.x * 256 + t;
  int v = (i < N_NODES) ? ((int)deg[i] - 1) : 0;
  s[t] = v;
  __syncthreads();
  for (int off = 1; off < 256; off <<= 1) {
    int add = (t >= off) ? s[t - off] : 0;
    __syncthreads();
    s[t] += add;
    __syncthreads();
  }
  if (i < N_NODES) rp[i] = s[t] - v;
  if (t == 255) bsums[blockIdx.x] = s[255];
}
__global__ __launch_bounds__(512) void k_scan2(const int* __restrict__ bsums,
                                               int* __restrict__ boffs) {
  __shared__ int s[512];
  int t = threadIdx.x;
  int v = (t < NB_NODES) ? bsums[t] : 0;
  s[t] = v;
  __syncthreads();
  for (int off = 1; off < 512; off <<= 1) {
    int add = (t >= off) ? s[t - off] : 0;
    __syncthreads();
    s[t] += add;
    __syncthreads();
  }
  boffs[t] = s[t] - v;
}
__global__ void k_scan3(int* __restrict__ rp, const int* __restrict__ boffs,
                        int* __restrict__ cursor) {
  int i = blockIdx.x * 256 + threadIdx.x;
  if (i < N_NODES) {
    int v = rp[i] + boffs[blockIdx.x];
    rp[i] = v;
    cursor[i] = v;
  }
  if (i == 0) rp[N_NODES] = N_EDGES;
}
__global__ void k_scatter(const int* __restrict__ ei,
    const float* __restrict__ dinv, int* __restrict__ cursor,
    int2* __restrict__ ed) {
  int e = blockIdx.x * 256 + threadIdx.x;
  if (e >= N_EDGES) return;
  unsigned s = (unsigned)ei[e];
  unsigned d = (unsigned)ei[N_EDGES + e];
  if (s >= N_NODES || d >= N_NODES) return;
  int pos = atomicAdd(&cursor[d], 1);
  if ((unsigned)pos < N_EDGES)
    ed[pos] = make_int2((int)s, __float_as_int(dinv[s] * dinv[d]));
}

// ---- W1 -> W1^T bf16 --------------------------------------------------------
__global__ void k_w1t(const float* __restrict__ W1, u16* __restrict__ w1t) {
  int n = blockIdx.x, k = threadIdx.x;         // 256 x 256
  w1t[n * 256 + k] = f2bf(W1[k * 256 + n]);
}

// ---- GEMM1 (MFMA bf16): y[100000,256]fp8 = x @ W1, 128x128 tile -------------
// A staged from f32 x with in-kernel bf16 convert (no separate pass).
__global__ __launch_bounds__(256) void k_gemm1(const float* __restrict__ x,
    const u16* __restrict__ w1t, unsigned char* __restrict__ y) {
  __shared__ char smem[20480];
  short* sA = (short*)smem;                    // [128][40] bf16 (pad 8)
  short* sB = (short*)(smem + 10240);          // [128][40]
  int tid = threadIdx.x;
  int wave = tid >> 6, lane = tid & 63;
  int lq = lane >> 4, lr = lane & 15;
  int wm = (wave >> 1) * 64, wn = (wave & 1) * 64;
  int row0 = blockIdx.x * 128;
  int col0 = blockIdx.y * 128;
  int sr = tid >> 1;                           // staging row 0..127
  int sh = (tid & 1) * 16;                     // k-half in elements
  int arow = row0 + sr;
  bool aval = arow < N_NODES;
  const float* axf = x + (size_t)arow * 256 + sh;
  const u16* bx = w1t + (size_t)(col0 + sr) * 256 + sh;
  f32x4 acc[4][4] = {};
  for (int k0 = 0; k0 < 256; k0 += 32) {
    float4 f0 = {}, f1 = {}, f2 = {}, f3 = {};
    if (aval) {
      f0 = *(const float4*)(axf + k0);
      f1 = *(const float4*)(axf + k0 + 4);
      f2 = *(const float4*)(axf + k0 + 8);
      f3 = *(const float4*)(axf + k0 + 12);
    }
    uint4 vb0 = *(const uint4*)(bx + k0);
    uint4 vb1 = *(const uint4*)(bx + k0 + 8);
    uint4 pa0, pa1;
    pa0.x = (u32)f2bf(f0.x) | ((u32)f2bf(f0.y) << 16);
    pa0.y = (u32)f2bf(f0.z) | ((u32)f2bf(f0.w) << 16);
    pa0.z = (u32)f2bf(f1.x) | ((u32)f2bf(f1.y) << 16);
    pa0.w = (u32)f2bf(f1.z) | ((u32)f2bf(f1.w) << 16);
    pa1.x = (u32)f2bf(f2.x) | ((u32)f2bf(f2.y) << 16);
    pa1.y = (u32)f2bf(f2.z) | ((u32)f2bf(f2.w) << 16);
    pa1.z = (u32)f2bf(f3.x) | ((u32)f2bf(f3.y) << 16);
    pa1.w = (u32)f2bf(f3.z) | ((u32)f2bf(f3.w) << 16);
    __syncthreads();
    *(uint4*)&sA[sr * 40 + sh] = pa0;
    *(uint4*)&sA[sr * 40 + sh + 8] = pa1;
    *(uint4*)&sB[sr * 40 + sh] = vb0;
    *(uint4*)&sB[sr * 40 + sh + 8] = vb1;
    __syncthreads();
    bf16x8 af[4], bfr[4];
#pragma unroll
    for (int mt = 0; mt < 4; ++mt)
      af[mt] = *(const bf16x8*)&sA[(wm + mt * 16 + lr) * 40 + lq * 8];
#pragma unroll
    for (int nt = 0; nt < 4; ++nt)
      bfr[nt] = *(const bf16x8*)&sB[(wn + nt * 16 + lr) * 40 + lq * 8];
#pragma unroll
    for (int mt = 0; mt < 4; ++mt)
#pragma unroll
      for (int nt = 0; nt < 4; ++nt)
        acc[mt][nt] = __builtin_amdgcn_mfma_f32_16x16x32_bf16(
            af[mt], bfr[nt], acc[mt][nt], 0, 0, 0);
  }
  // epilogue: fp8 via LDS transpose (C/D: col=lane&15, row=(lane>>4)*4+reg)
  __syncthreads();
#pragma unroll
  for (int mt = 0; mt < 4; ++mt)
#pragma unroll
    for (int nt = 0; nt < 4; ++nt) {
      int c = wn + nt * 16 + lr;
#pragma unroll
      for (int i = 0; i < 4; ++i) {
        int r = wm + mt * 16 + lq * 4 + i;
        int pk = __builtin_amdgcn_cvt_pk_fp8_f32(acc[mt][nt][i], acc[mt][nt][i], 0, false);
        smem[r * 144 + c] = (char)(pk & 0xFF);
      }
    }
  __syncthreads();
  if (aval) {
    unsigned char* dst = y + (size_t)arow * 256 + col0 + (tid & 1) * 64;
    const char* srcp = smem + sr * 144 + (tid & 1) * 64;
#pragma unroll
    for (int j = 0; j < 4; ++j)
      ((uint4*)dst)[j] = *(const uint4*)(srcp + j * 16);
  }
}

// ---- SpMM1: h1 = relu(A @ y + b1), y fp8, one wave per row, 4x edge ILP -----
__global__ __launch_bounds__(256) void k_spmm1(const u32* __restrict__ y32,
    const int2* __restrict__ ed, const int* __restrict__ rp,
    const float* __restrict__ dinv, const float* __restrict__ b1,
    u16* __restrict__ h1) {
  int lane = threadIdx.x & 63;
  int row = (blockIdx.x << 2) + (threadIdx.x >> 6);
  float di = dinv[row];
  float wsl = di * di;
  u32 v = y32[(size_t)row * 64 + lane];
  f32x2 lo = __builtin_amdgcn_cvt_pk_f32_fp8(v, false);
  f32x2 hi = __builtin_amdgcn_cvt_pk_f32_fp8(v, true);
  float a0 = wsl * lo.x, a1 = wsl * lo.y, a2 = wsl * hi.x, a3 = wsl * hi.y;
  int e = rp[row], e1 = rp[row + 1];
  for (; e + 4 <= e1; e += 4) {
    int2 m0 = ed[e];
    int2 m1 = ed[e + 1];
    int2 m2 = ed[e + 2];
    int2 m3 = ed[e + 3];
    u32 u0 = y32[(size_t)m0.x * 64 + lane];
    u32 u1 = y32[(size_t)m1.x * 64 + lane];
    u32 u2 = y32[(size_t)m2.x * 64 + lane];
    u32 u3 = y32[(size_t)m3.x * 64 + lane];
    float w0 = __int_as_float(m0.y), w1 = __int_as_float(m1.y);
    float w2 = __int_as_float(m2.y), w3 = __int_as_float(m3.y);
    f32x2 l0 = __builtin_amdgcn_cvt_pk_f32_fp8(u0, false);
    f32x2 h0 = __builtin_amdgcn_cvt_pk_f32_fp8(u0, true);
    f32x2 l1 = __builtin_amdgcn_cvt_pk_f32_fp8(u1, false);
    f32x2 h1v = __builtin_amdgcn_cvt_pk_f32_fp8(u1, true);
    f32x2 l2 = __builtin_amdgcn_cvt_pk_f32_fp8(u2, false);
    f32x2 h2 = __builtin_amdgcn_cvt_pk_f32_fp8(u2, true);
    f32x2 l3 = __builtin_amdgcn_cvt_pk_f32_fp8(u3, false);
    f32x2 h3 = __builtin_amdgcn_cvt_pk_f32_fp8(u3, true);
    a0 += w0 * l0.x + w1 * l1.x + w2 * l2.x + w3 * l3.x;
    a1 += w0 * l0.y + w1 * l1.y + w2 * l2.y + w3 * l3.y;
    a2 += w0 * h0.x + w1 * h1v.x + w2 * h2.x + w3 * h3.x;
    a3 += w0 * h0.y + w1 * h1v.y + w2 * h2.y + w3 * h3.y;
  }
  for (; e < e1; ++e) {
    int2 m = ed[e];
    u32 u = y32[(size_t)m.x * 64 + lane];
    float w = __int_as_float(m.y);
    f32x2 l = __builtin_amdgcn_cvt_pk_f32_fp8(u, false);
    f32x2 h = __builtin_amdgcn_cvt_pk_f32_fp8(u, true);
    a0 += w * l.x; a1 += w * l.y; a2 += w * h.x; a3 += w * h.y;
  }
  float4 bb = *(const float4*)(b1 + lane * 4);
  a0 = fmaxf(a0 + bb.x, 0.f);
  a1 = fmaxf(a1 + bb.y, 0.f);
  a2 = fmaxf(a2 + bb.z, 0.f);
  a3 = fmaxf(a3 + bb.w, 0.f);
  ushort4 o;
  o.x = f2bf(a0); o.y = f2bf(a1); o.z = f2bf(a2); o.w = f2bf(a3);
  *(ushort4*)(h1 + (size_t)row * HID + lane * 4) = o;
}

// ---- GEMM2: z[100000,40]bf16 = h1 @ W2, W2 staged in LDS --------------------
__global__ __launch_bounds__(256) void k_gemm2(const u16* __restrict__ h1,
    const float* __restrict__ W2, u16* __restrict__ zb) {
  __shared__ float W2s[HID * NC];   // 40 KB
  for (int j = threadIdx.x; j < HID * NC; j += 256) W2s[j] = W2[j];
  __syncthreads();
  int idx = blockIdx.x * 256 + threadIdx.x;
  int r = idx / 10, q = idx % 10;
  if (r >= N_NODES) return;
  const u16* hr = h1 + (size_t)r * HID;
  float ax = 0.f, ay = 0.f, az = 0.f, aw = 0.f;
  for (int k = 0; k < HID; k += 4) {
    ushort4 hv = *(const ushort4*)(hr + k);
    float h0 = bf2f(hv.x), h1v = bf2f(hv.y), h2 = bf2f(hv.z), h3 = bf2f(hv.w);
    float4 w0 = *(const float4*)&W2s[(k + 0) * NC + q * 4];
    float4 w1 = *(const float4*)&W2s[(k + 1) * NC + q * 4];
    float4 w2 = *(const float4*)&W2s[(k + 2) * NC + q * 4];
    float4 w3 = *(const float4*)&W2s[(k + 3) * NC + q * 4];
    ax += h0 * w0.x + h1v * w1.x + h2 * w2.x + h3 * w3.x;
    ay += h0 * w0.y + h1v * w1.y + h2 * w2.y + h3 * w3.y;
    az += h0 * w0.z + h1v * w1.z + h2 * w2.z + h3 * w3.z;
    aw += h0 * w0.w + h1v * w1.w + h2 * w2.w + h3 * w3.w;
  }
  ushort4 o;
  o.x = f2bf(ax); o.y = f2bf(ay); o.z = f2bf(az); o.w = f2bf(aw);
  *(ushort4*)(zb + (size_t)r * NC + q * 4) = o;
}

// ---- SpMM2 + bias + log_softmax fused (z bf16), 4x edge ILP -----------------
__global__ __launch_bounds__(256) void k_spmm2(const u16* __restrict__ zb,
    const int2* __restrict__ ed, const int* __restrict__ rp,
    const float* __restrict__ dinv, const float* __restrict__ b2,
    float* __restrict__ out) {
  int lane = threadIdx.x & 63;
  int row = (blockIdx.x << 2) + (threadIdx.x >> 6);
  int col = (lane < NC) ? lane : 0;
  float di = dinv[row];
  float acc = di * di * bf2f(zb[(size_t)row * NC + col]);
  int e = rp[row], e1 = rp[row + 1];
  for (; e + 4 <= e1; e += 4) {
    int2 m0 = ed[e];
    int2 m1 = ed[e + 1];
    int2 m2 = ed[e + 2];
    int2 m3 = ed[e + 3];
    u16 z0 = zb[(size_t)m0.x * NC + col];
    u16 z1 = zb[(size_t)m1.x * NC + col];
    u16 z2 = zb[(size_t)m2.x * NC + col];
    u16 z3 = zb[(size_t)m3.x * NC + col];
    acc += __int_as_float(m0.y) * bf2f(z0) + __int_as_float(m1.y) * bf2f(z1) +
           __int_as_float(m2.y) * bf2f(z2) + __int_as_float(m3.y) * bf2f(z3);
  }
  for (; e < e1; ++e) {
    int2 m = ed[e];
    acc += __int_as_float(m.y) * bf2f(zb[(size_t)m.x * NC + col]);
  }
  acc += b2[col];
  float mv = (lane < NC) ? acc : -3.0e38f;
  for (int off = 32; off > 0; off >>= 1) mv = fmaxf(mv, __shfl_xor(mv, off));
  float ex = (lane < NC) ? expf(acc - mv) : 0.f;
  float sum = ex;
  for (int off = 32; off > 0; off >>= 1) sum += __shfl_xor(sum, off);
  float res = acc - mv - logf(sum);
  if (lane < NC) out[(size_t)row * NC + lane] = res;
}

extern "C" void kernel_launch(void* const* d_in, const int* in_sizes, int n_in,
                              void* d_out, int out_size, void* d_ws, size_t ws_size,
                              hipStream_t stream) {
  const float* x  = (const float*)d_in[0];
  const int*   ei = (const int*)d_in[1];
  const float* W1 = (const float*)d_in[2];
  const float* b1 = (const float*)d_in[3];
  const float* W2 = (const float*)d_in[4];
  const float* b2 = (const float*)d_in[5];
  float* out = (float*)d_out;

  char* ws = (char*)d_ws;
  size_t off = 0;
  auto alloc = [&](size_t bytes) {
    char* p = ws + off;
    off = (off + bytes + 255) & ~(size_t)255;
    return p;
  };
  float* deg    = (float*)alloc((size_t)N_NODES * 4);
  float* dinv   = (float*)alloc((size_t)N_NODES * 4);
  int*   rp     = (int*)  alloc((size_t)(N_NODES + 1) * 4);
  int*   cursor = (int*)  alloc((size_t)N_NODES * 4);
  int*   bsums  = (int*)  alloc((size_t)NB_NODES * 4);
  int*   boffs  = (int*)  alloc((size_t)512 * 4);
  int2*  ed     = (int2*) alloc((size_t)N_EDGES * 8);           // 25.6 MB
  unsigned char* y = (unsigned char*)alloc((size_t)N_NODES * 256); // 25.6 MB fp8
  u16*   w1t    = (u16*)  alloc((size_t)256 * 256 * 2);
  u16*   h1     = (u16*)  alloc((size_t)N_NODES * HID * 2);     // 51.2 MB
  u16*   zb     = (u16*)  alloc((size_t)N_NODES * NC * 2);      // 8 MB

  k_init<<<NB_NODES, 256, 0, stream>>>(deg);
  k_count<<<EB, 256, 0, stream>>>(ei, deg);
  k_dinv<<<NB_NODES, 256, 0, stream>>>(deg, dinv);
  k_scan1<<<NB_NODES, 256, 0, stream>>>(deg, rp, bsums);
  k_scan2<<<1, 512, 0, stream>>>(bsums, boffs);
  k_scan3<<<NB_NODES, 256, 0, stream>>>(rp, boffs, cursor);
  k_scatter<<<EB, 256, 0, stream>>>(ei, dinv, cursor, ed);
  k_w1t<<<256, 256, 0, stream>>>(W1, w1t);
  k_gemm1<<<dim3((N_NODES + 127) / 128, 2), 256, 0, stream>>>(x, w1t, y);
  k_spmm1<<<N_NODES / 4, 256, 0, stream>>>((const u32*)y, ed, rp, dinv, b1, h1);
  k_gemm2<<<(N_NODES * 10 + 255) / 256, 256, 0, stream>>>(h1, W2, zb);
  k_spmm2<<<N_NODES / 4, 256, 0, stream>>>(zb, ed, rp, dinv, b2, out);
}

// Round 5
// 763.743 us; speedup vs baseline: 1.4064x; 1.0504x over previous
//
#include <hip/hip_runtime.h>
#include <hip/hip_bf16.h>

#define N_NODES 100000
#define N_EDGES 3200000
#define D_IN 256
#define HID 256
#define NC 40
#define NB_NODES ((N_NODES + 255) / 256)   /* 391 node-blocks */
#define EB ((N_EDGES + 255) / 256)         /* 12500 edge-blocks */

typedef unsigned short u16;
typedef unsigned int u32;
typedef __attribute__((ext_vector_type(8))) short bf16x8;
typedef __attribute__((ext_vector_type(4))) float f32x4;
typedef __attribute__((ext_vector_type(2))) float f32x2;

static __device__ __forceinline__ float bf2f(u16 u) {
  union { unsigned int i; float f; } c; c.i = ((unsigned int)u) << 16; return c.f;
}
static __device__ __forceinline__ u16 f2bf(float f) {
  union { float f; unsigned int i; } c; c.f = f;
  unsigned int x = c.i;
  x += 0x7fffu + ((x >> 16) & 1u);   // round-to-nearest-even
  return (u16)(x >> 16);
}

// ---- degree (int histogram; self-loop folded in later) ----------------------
__global__ void k_init(int* __restrict__ deg) {
  int i = blockIdx.x * 256 + threadIdx.x;
  if (i < N_NODES) deg[i] = 0;
}
__global__ void k_count(const int* __restrict__ ei, int* __restrict__ deg) {
  int e = blockIdx.x * 256 + threadIdx.x;
  if (e >= N_EDGES) return;
  unsigned d = (unsigned)ei[N_EDGES + e];
  if (d < N_NODES) atomicAdd(&deg[d], 1);   // native int atomic, no CAS loop
}
__global__ void k_dinv(const int* __restrict__ deg, float* __restrict__ dinv) {
  int i = blockIdx.x * 256 + threadIdx.x;
  if (i < N_NODES) dinv[i] = rsqrtf((float)deg[i] + 1.0f);  // +1 self-loop
}

// ---- CSR build (rp = exclusive scan of edge in-degree) ----------------------
__global__ __launch_bounds__(256) void k_scan1(const int* __restrict__ deg,
    int* __restrict__ rp, int* __restrict__ bsums) {
  __shared__ int s[256];
  int t = threadIdx.x, i = blockIdx.x * 256 + t;
  int v = (i < N_NODES) ? deg[i] : 0;
  s[t] = v;
  __syncthreads();
  for (int off = 1; off < 256; off <<= 1) {
    int add = (t >= off) ? s[t - off] : 0;
    __syncthreads();
    s[t] += add;
    __syncthreads();
  }
  if (i < N_NODES) rp[i] = s[t] - v;
  if (t == 255) bsums[blockIdx.x] = s[255];
}
__global__ __launch_bounds__(512) void k_scan2(const int* __restrict__ bsums,
                                               int* __restrict__ boffs) {
  __shared__ int s[512];
  int t = threadIdx.x;
  int v = (t < NB_NODES) ? bsums[t] : 0;
  s[t] = v;
  __syncthreads();
  for (int off = 1; off < 512; off <<= 1) {
    int add = (t >= off) ? s[t - off] : 0;
    __syncthreads();
    s[t] += add;
    __syncthreads();
  }
  boffs[t] = s[t] - v;
}
__global__ void k_scan3(int* __restrict__ rp, const int* __restrict__ boffs,
                        int* __restrict__ cursor) {
  int i = blockIdx.x * 256 + threadIdx.x;
  if (i < N_NODES) {
    int v = rp[i] + boffs[blockIdx.x];
    rp[i] = v;
    cursor[i] = v;
  }
  if (i == 0) rp[N_NODES] = N_EDGES;
}
__global__ void k_scatter(const int* __restrict__ ei,
    const float* __restrict__ dinv, int* __restrict__ cursor,
    int2* __restrict__ ed) {
  int e = blockIdx.x * 256 + threadIdx.x;
  if (e >= N_EDGES) return;
  unsigned s = (unsigned)ei[e];
  unsigned d = (unsigned)ei[N_EDGES + e];
  if (s >= N_NODES || d >= N_NODES) return;
  int pos = atomicAdd(&cursor[d], 1);
  if ((unsigned)pos < N_EDGES)
    ed[pos] = make_int2((int)s, __float_as_int(dinv[s] * dinv[d]));
}

// ---- W1 -> W1^T bf16 --------------------------------------------------------
__global__ void k_w1t(const float* __restrict__ W1, u16* __restrict__ w1t) {
  int n = blockIdx.x, k = threadIdx.x;         // 256 x 256
  w1t[n * 256 + k] = f2bf(W1[k * 256 + n]);
}

// ---- GEMM1 (MFMA bf16): y[100000,256]fp8 = x @ W1, 128x128 tile -------------
__global__ __launch_bounds__(256) void k_gemm1(const float* __restrict__ x,
    const u16* __restrict__ w1t, unsigned char* __restrict__ y) {
  __shared__ char smem[20480];
  short* sA = (short*)smem;                    // [128][40] bf16 (pad 8)
  short* sB = (short*)(smem + 10240);          // [128][40]
  int tid = threadIdx.x;
  int wave = tid >> 6, lane = tid & 63;
  int lq = lane >> 4, lr = lane & 15;
  int wm = (wave >> 1) * 64, wn = (wave & 1) * 64;
  int row0 = blockIdx.x * 128;
  int col0 = blockIdx.y * 128;
  int sr = tid >> 1;                           // staging row 0..127
  int sh = (tid & 1) * 16;                     // k-half in elements
  int arow = row0 + sr;
  bool aval = arow < N_NODES;
  const float* axf = x + (size_t)arow * 256 + sh;
  const u16* bx = w1t + (size_t)(col0 + sr) * 256 + sh;
  f32x4 acc[4][4] = {};
  for (int k0 = 0; k0 < 256; k0 += 32) {
    float4 f0 = {}, f1 = {}, f2 = {}, f3 = {};
    if (aval) {
      f0 = *(const float4*)(axf + k0);
      f1 = *(const float4*)(axf + k0 + 4);
      f2 = *(const float4*)(axf + k0 + 8);
      f3 = *(const float4*)(axf + k0 + 12);
    }
    uint4 vb0 = *(const uint4*)(bx + k0);
    uint4 vb1 = *(const uint4*)(bx + k0 + 8);
    uint4 pa0, pa1;
    pa0.x = (u32)f2bf(f0.x) | ((u32)f2bf(f0.y) << 16);
    pa0.y = (u32)f2bf(f0.z) | ((u32)f2bf(f0.w) << 16);
    pa0.z = (u32)f2bf(f1.x) | ((u32)f2bf(f1.y) << 16);
    pa0.w = (u32)f2bf(f1.z) | ((u32)f2bf(f1.w) << 16);
    pa1.x = (u32)f2bf(f2.x) | ((u32)f2bf(f2.y) << 16);
    pa1.y = (u32)f2bf(f2.z) | ((u32)f2bf(f2.w) << 16);
    pa1.z = (u32)f2bf(f3.x) | ((u32)f2bf(f3.y) << 16);
    pa1.w = (u32)f2bf(f3.z) | ((u32)f2bf(f3.w) << 16);
    __syncthreads();
    *(uint4*)&sA[sr * 40 + sh] = pa0;
    *(uint4*)&sA[sr * 40 + sh + 8] = pa1;
    *(uint4*)&sB[sr * 40 + sh] = vb0;
    *(uint4*)&sB[sr * 40 + sh + 8] = vb1;
    __syncthreads();
    bf16x8 af[4], bfr[4];
#pragma unroll
    for (int mt = 0; mt < 4; ++mt)
      af[mt] = *(const bf16x8*)&sA[(wm + mt * 16 + lr) * 40 + lq * 8];
#pragma unroll
    for (int nt = 0; nt < 4; ++nt)
      bfr[nt] = *(const bf16x8*)&sB[(wn + nt * 16 + lr) * 40 + lq * 8];
#pragma unroll
    for (int mt = 0; mt < 4; ++mt)
#pragma unroll
      for (int nt = 0; nt < 4; ++nt)
        acc[mt][nt] = __builtin_amdgcn_mfma_f32_16x16x32_bf16(
            af[mt], bfr[nt], acc[mt][nt], 0, 0, 0);
  }
  // epilogue: fp8 via LDS transpose (C/D: col=lane&15, row=(lane>>4)*4+reg)
  __syncthreads();
#pragma unroll
  for (int mt = 0; mt < 4; ++mt)
#pragma unroll
    for (int nt = 0; nt < 4; ++nt) {
      int c = wn + nt * 16 + lr;
#pragma unroll
      for (int i = 0; i < 4; ++i) {
        int r = wm + mt * 16 + lq * 4 + i;
        int pk = __builtin_amdgcn_cvt_pk_fp8_f32(acc[mt][nt][i], acc[mt][nt][i], 0, false);
        smem[r * 144 + c] = (char)(pk & 0xFF);
      }
    }
  __syncthreads();
  if (aval) {
    unsigned char* dst = y + (size_t)arow * 256 + col0 + (tid & 1) * 64;
    const char* srcp = smem + sr * 144 + (tid & 1) * 64;
#pragma unroll
    for (int j = 0; j < 4; ++j)
      ((uint4*)dst)[j] = *(const uint4*)(srcp + j * 16);
  }
}

// ---- SpMM1: h1 = relu(A @ y + b1), y fp8, one wave per row, 4x edge ILP -----
__global__ __launch_bounds__(256) void k_spmm1(const u32* __restrict__ y32,
    const int2* __restrict__ ed, const int* __restrict__ rp,
    const float* __restrict__ dinv, const float* __restrict__ b1,
    u16* __restrict__ h1) {
  int lane = threadIdx.x & 63;
  int row = (blockIdx.x << 2) + (threadIdx.x >> 6);
  float di = dinv[row];
  float wsl = di * di;
  u32 v = y32[(size_t)row * 64 + lane];
  f32x2 lo = __builtin_amdgcn_cvt_pk_f32_fp8(v, false);
  f32x2 hi = __builtin_amdgcn_cvt_pk_f32_fp8(v, true);
  float a0 = wsl * lo.x, a1 = wsl * lo.y, a2 = wsl * hi.x, a3 = wsl * hi.y;
  int e = rp[row], e1 = rp[row + 1];
  for (; e + 4 <= e1; e += 4) {
    int2 m0 = ed[e];
    int2 m1 = ed[e + 1];
    int2 m2 = ed[e + 2];
    int2 m3 = ed[e + 3];
    u32 u0 = y32[(size_t)m0.x * 64 + lane];
    u32 u1 = y32[(size_t)m1.x * 64 + lane];
    u32 u2 = y32[(size_t)m2.x * 64 + lane];
    u32 u3 = y32[(size_t)m3.x * 64 + lane];
    float w0 = __int_as_float(m0.y), w1 = __int_as_float(m1.y);
    float w2 = __int_as_float(m2.y), w3 = __int_as_float(m3.y);
    f32x2 l0 = __builtin_amdgcn_cvt_pk_f32_fp8(u0, false);
    f32x2 h0 = __builtin_amdgcn_cvt_pk_f32_fp8(u0, true);
    f32x2 l1 = __builtin_amdgcn_cvt_pk_f32_fp8(u1, false);
    f32x2 h1v = __builtin_amdgcn_cvt_pk_f32_fp8(u1, true);
    f32x2 l2 = __builtin_amdgcn_cvt_pk_f32_fp8(u2, false);
    f32x2 h2 = __builtin_amdgcn_cvt_pk_f32_fp8(u2, true);
    f32x2 l3 = __builtin_amdgcn_cvt_pk_f32_fp8(u3, false);
    f32x2 h3 = __builtin_amdgcn_cvt_pk_f32_fp8(u3, true);
    a0 += w0 * l0.x + w1 * l1.x + w2 * l2.x + w3 * l3.x;
    a1 += w0 * l0.y + w1 * l1.y + w2 * l2.y + w3 * l3.y;
    a2 += w0 * h0.x + w1 * h1v.x + w2 * h2.x + w3 * h3.x;
    a3 += w0 * h0.y + w1 * h1v.y + w2 * h2.y + w3 * h3.y;
  }
  for (; e < e1; ++e) {
    int2 m = ed[e];
    u32 u = y32[(size_t)m.x * 64 + lane];
    float w = __int_as_float(m.y);
    f32x2 l = __builtin_amdgcn_cvt_pk_f32_fp8(u, false);
    f32x2 h = __builtin_amdgcn_cvt_pk_f32_fp8(u, true);
    a0 += w * l.x; a1 += w * l.y; a2 += w * h.x; a3 += w * h.y;
  }
  float4 bb = *(const float4*)(b1 + lane * 4);
  a0 = fmaxf(a0 + bb.x, 0.f);
  a1 = fmaxf(a1 + bb.y, 0.f);
  a2 = fmaxf(a2 + bb.z, 0.f);
  a3 = fmaxf(a3 + bb.w, 0.f);
  ushort4 o;
  o.x = f2bf(a0); o.y = f2bf(a1); o.z = f2bf(a2); o.w = f2bf(a3);
  *(ushort4*)(h1 + (size_t)row * HID + lane * 4) = o;
}

// ---- GEMM2: z[100000,40]bf16 = h1 @ W2, W2 staged in LDS --------------------
__global__ __launch_bounds__(256) void k_gemm2(const u16* __restrict__ h1,
    const float* __restrict__ W2, u16* __restrict__ zb) {
  __shared__ float W2s[HID * NC];   // 40 KB
  for (int j = threadIdx.x; j < HID * NC; j += 256) W2s[j] = W2[j];
  __syncthreads();
  int idx = blockIdx.x * 256 + threadIdx.x;
  int r = idx / 10, q = idx % 10;
  if (r >= N_NODES) return;
  const u16* hr = h1 + (size_t)r * HID;
  float ax = 0.f, ay = 0.f, az = 0.f, aw = 0.f;
  for (int k = 0; k < HID; k += 4) {
    ushort4 hv = *(const ushort4*)(hr + k);
    float h0 = bf2f(hv.x), h1v = bf2f(hv.y), h2 = bf2f(hv.z), h3 = bf2f(hv.w);
    float4 w0 = *(const float4*)&W2s[(k + 0) * NC + q * 4];
    float4 w1 = *(const float4*)&W2s[(k + 1) * NC + q * 4];
    float4 w2 = *(const float4*)&W2s[(k + 2) * NC + q * 4];
    float4 w3 = *(const float4*)&W2s[(k + 3) * NC + q * 4];
    ax += h0 * w0.x + h1v * w1.x + h2 * w2.x + h3 * w3.x;
    ay += h0 * w0.y + h1v * w1.y + h2 * w2.y + h3 * w3.y;
    az += h0 * w0.z + h1v * w1.z + h2 * w2.z + h3 * w3.z;
    aw += h0 * w0.w + h1v * w1.w + h2 * w2.w + h3 * w3.w;
  }
  ushort4 o;
  o.x = f2bf(ax); o.y = f2bf(ay); o.z = f2bf(az); o.w = f2bf(aw);
  *(ushort4*)(zb + (size_t)r * NC + q * 4) = o;
}

// ---- SpMM2 + bias + log_softmax fused (z bf16), 4x edge ILP -----------------
__global__ __launch_bounds__(256) void k_spmm2(const u16* __restrict__ zb,
    const int2* __restrict__ ed, const int* __restrict__ rp,
    const float* __restrict__ dinv, const float* __restrict__ b2,
    float* __restrict__ out) {
  int lane = threadIdx.x & 63;
  int row = (blockIdx.x << 2) + (threadIdx.x >> 6);
  int col = (lane < NC) ? lane : 0;
  float di = dinv[row];
  float acc = di * di * bf2f(zb[(size_t)row * NC + col]);
  int e = rp[row], e1 = rp[row + 1];
  for (; e + 4 <= e1; e += 4) {
    int2 m0 = ed[e];
    int2 m1 = ed[e + 1];
    int2 m2 = ed[e + 2];
    int2 m3 = ed[e + 3];
    u16 z0 = zb[(size_t)m0.x * NC + col];
    u16 z1 = zb[(size_t)m1.x * NC + col];
    u16 z2 = zb[(size_t)m2.x * NC + col];
    u16 z3 = zb[(size_t)m3.x * NC + col];
    acc += __int_as_float(m0.y) * bf2f(z0) + __int_as_float(m1.y) * bf2f(z1) +
           __int_as_float(m2.y) * bf2f(z2) + __int_as_float(m3.y) * bf2f(z3);
  }
  for (; e < e1; ++e) {
    int2 m = ed[e];
    acc += __int_as_float(m.y) * bf2f(zb[(size_t)m.x * NC + col]);
  }
  acc += b2[col];
  float mv = (lane < NC) ? acc : -3.0e38f;
  for (int off = 32; off > 0; off >>= 1) mv = fmaxf(mv, __shfl_xor(mv, off));
  float ex = (lane < NC) ? expf(acc - mv) : 0.f;
  float sum = ex;
  for (int off = 32; off > 0; off >>= 1) sum += __shfl_xor(sum, off);
  float res = acc - mv - logf(sum);
  if (lane < NC) out[(size_t)row * NC + lane] = res;
}

extern "C" void kernel_launch(void* const* d_in, const int* in_sizes, int n_in,
                              void* d_out, int out_size, void* d_ws, size_t ws_size,
                              hipStream_t stream) {
  const float* x  = (const float*)d_in[0];
  const int*   ei = (const int*)d_in[1];
  const float* W1 = (const float*)d_in[2];
  const float* b1 = (const float*)d_in[3];
  const float* W2 = (const float*)d_in[4];
  const float* b2 = (const float*)d_in[5];
  float* out = (float*)d_out;

  char* ws = (char*)d_ws;
  size_t off = 0;
  auto alloc = [&](size_t bytes) {
    char* p = ws + off;
    off = (off + bytes + 255) & ~(size_t)255;
    return p;
  };
  int*   deg    = (int*)  alloc((size_t)N_NODES * 4);
  float* dinv   = (float*)alloc((size_t)N_NODES * 4);
  int*   rp     = (int*)  alloc((size_t)(N_NODES + 1) * 4);
  int*   cursor = (int*)  alloc((size_t)N_NODES * 4);
  int*   bsums  = (int*)  alloc((size_t)NB_NODES * 4);
  int*   boffs  = (int*)  alloc((size_t)512 * 4);
  int2*  ed     = (int2*) alloc((size_t)N_EDGES * 8);           // 25.6 MB
  unsigned char* y = (unsigned char*)alloc((size_t)N_NODES * 256); // 25.6 MB fp8
  u16*   w1t    = (u16*)  alloc((size_t)256 * 256 * 2);
  u16*   h1     = (u16*)  alloc((size_t)N_NODES * HID * 2);     // 51.2 MB
  u16*   zb     = (u16*)  alloc((size_t)N_NODES * NC * 2);      // 8 MB

  k_init<<<NB_NODES, 256, 0, stream>>>(deg);
  k_count<<<EB, 256, 0, stream>>>(ei, deg);
  k_dinv<<<NB_NODES, 256, 0, stream>>>(deg, dinv);
  k_scan1<<<NB_NODES, 256, 0, stream>>>(deg, rp, bsums);
  k_scan2<<<1, 512, 0, stream>>>(bsums, boffs);
  k_scan3<<<NB_NODES, 256, 0, stream>>>(rp, boffs, cursor);
  k_scatter<<<EB, 256, 0, stream>>>(ei, dinv, cursor, ed);
  k_w1t<<<256, 256, 0, stream>>>(W1, w1t);
  k_gemm1<<<dim3((N_NODES + 127) / 128, 2), 256, 0, stream>>>(x, w1t, y);
  k_spmm1<<<N_NODES / 4, 256, 0, stream>>>((const u32*)y, ed, rp, dinv, b1, h1);
  k_gemm2<<<(N_NODES * 10 + 255) / 256, 256, 0, stream>>>(h1, W2, zb);
  k_spmm2<<<N_NODES / 4, 256, 0, stream>>>(zb, ed, rp, dinv, b2, out);
}